// Round 4
// baseline (13136.922 us; speedup 1.0000x reference)
//
#include <hip/hip_runtime.h>
#include <hip/hip_bf16.h>
#include <stdint.h>

typedef __attribute__((ext_vector_type(8))) short short8;
typedef __attribute__((ext_vector_type(4))) float f32x4;
typedef __attribute__((ext_vector_type(4))) unsigned int u32x4;

__device__ __forceinline__ unsigned short f2bf(float x) {
  unsigned int u = __builtin_bit_cast(unsigned int, x);
  u += 0x7FFFu + ((u >> 16) & 1u);           // round-to-nearest-even
  return (unsigned short)(u >> 16);
}
__device__ __forceinline__ float bf2f(unsigned short u) {
  unsigned int v = ((unsigned int)u) << 16;
  return __builtin_bit_cast(float, v);
}
__device__ __forceinline__ unsigned int pk2(float a, float b) {
  return (unsigned int)f2bf(a) | ((unsigned int)f2bf(b) << 16);
}
__device__ __forceinline__ float sigm(float x) {
  return __builtin_amdgcn_rcpf(1.0f + __builtin_amdgcn_exp2f(-1.44269504f * x));
}
__device__ __forceinline__ float tanh_(float x) {
  return 2.0f * __builtin_amdgcn_rcpf(1.0f + __builtin_amdgcn_exp2f(-2.88539008f * x)) - 1.0f;
}
__device__ __forceinline__ f32x4 mfma16(short8 a, short8 b, f32x4 c) {
  return __builtin_amdgcn_mfma_f32_16x16x32_bf16(a, b, c, 0, 0, 0);
}
__device__ __forceinline__ short8 bc(u32x4 v) { return __builtin_bit_cast(short8, v); }

// ---------------------------------------------------------------------------
// prep: bf16 transposed weight images, fused bias, zero hbuf + flags.
// Gate order: 0=f, 1=i, 2=g, 3=o.
// WxT: [2048 n][512 k]   WhT: [32 wg][64 j][512 k]  (j = gate*16 + hc_local)
// flags: 32 u16 (one per WG, packed in one 64B line). hbuf: 2 x [64][512] bf16
// ---------------------------------------------------------------------------
__global__ void lstm_prep(
    const float* __restrict__ Wif, const float* __restrict__ Wii,
    const float* __restrict__ Wig, const float* __restrict__ Wio,
    const float* __restrict__ Whf, const float* __restrict__ Whi,
    const float* __restrict__ Whg, const float* __restrict__ Who,
    const float* __restrict__ bif, const float* __restrict__ bhf,
    const float* __restrict__ bii, const float* __restrict__ bhi,
    const float* __restrict__ big, const float* __restrict__ bhg,
    const float* __restrict__ bio, const float* __restrict__ bho,
    unsigned short* __restrict__ WxT, unsigned short* __restrict__ WhT,
    float* __restrict__ bias, unsigned short* __restrict__ hbuf,
    unsigned short* __restrict__ flags)
{
  const long NWX = 2048L * 512, NWH = 32L * 64 * 512;
  const long NH = 2L * 64 * 512;
  long total = NWX + NWH + 2048 + NH + 32;
  for (long i = (long)blockIdx.x * blockDim.x + threadIdx.x; i < total;
       i += (long)gridDim.x * blockDim.x) {
    if (i < NWX) {
      int n = (int)(i >> 9), k = (int)(i & 511);
      int g = n >> 9, hc = n & 511;
      const float* W = (g == 0) ? Wif : (g == 1) ? Wii : (g == 2) ? Wig : Wio;
      WxT[i] = f2bf(W[k * 512 + hc]);
    } else if (i < NWX + NWH) {
      long r = i - NWX;
      int wg = (int)(r >> 15); int rest = (int)(r & 32767);
      int j = rest >> 9, k = rest & 511;
      int g = j >> 4, hc = wg * 16 + (j & 15);
      const float* W = (g == 0) ? Whf : (g == 1) ? Whi : (g == 2) ? Whg : Who;
      WhT[r] = f2bf(W[k * 512 + hc]);
    } else if (i < NWX + NWH + 2048) {
      int n = (int)(i - NWX - NWH);
      int g = n >> 9, hc = n & 511;
      const float* bi = (g == 0) ? bif : (g == 1) ? bii : (g == 2) ? big : bio;
      const float* bh = (g == 0) ? bhf : (g == 1) ? bhi : (g == 2) ? bhg : bho;
      bias[n] = bi[hc] + bh[hc];
    } else if (i < NWX + NWH + 2048 + NH) {
      hbuf[i - NWX - NWH - 2048] = 0;
    } else {
      flags[i - NWX - NWH - 2048 - NH] = 0;
    }
  }
}

// ---------------------------------------------------------------------------
// x-projection GEMM: (B*T, 512) @ (512, 2048) + bias -> bf16, written in the
// recurrent kernel's per-lane-packed layout:
//   xp[ ((t*32 + wg)*4 + g)*1024 + lane*16 + mt*4 + i ]
// (wg = hc>>4, g = gate, lane = hi*16 + (hc&15), mt = b>>4, i = b&3, hi=(b>>2)&3)
// ---------------------------------------------------------------------------
#define GP 56  // LDS row stride (elems): 112B, 16B-aligned, 2-way banks

__global__ __launch_bounds__(256) void lstm_xproj(
    const float* __restrict__ x, const unsigned short* __restrict__ WxT,
    const float* __restrict__ bias, unsigned short* __restrict__ xp)
{
  __shared__ unsigned short As[128 * GP];
  __shared__ unsigned short Bs[128 * GP];
  int bid = blockIdx.x;
  int mt = bid & 511, nt = bid >> 9;          // 512 m-tiles, 16 n-tiles
  int m0 = mt << 7, n0 = nt << 7;
  int tid = threadIdx.x, lane = tid & 63, w = tid >> 6;
  int wm = w >> 1, wn = w & 1;
  int l15 = lane & 15, hi4 = lane >> 4;

  f32x4 acc[4][4] = {};
  int srow = tid >> 1, skq = (tid & 1) << 4;  // each thread: 1 row, 16 k
  const float* xa = x + (size_t)(m0 + srow) * 512 + skq;
  const unsigned short* bsrc = WxT + (size_t)(n0 + srow) * 512 + skq;
  unsigned short* adst = As + srow * GP + skq;
  unsigned short* bdst = Bs + srow * GP + skq;

  for (int kt = 0; kt < 16; ++kt) {
    f32x4 a0 = *(const f32x4*)(xa + kt * 32);
    f32x4 a1 = *(const f32x4*)(xa + kt * 32 + 4);
    f32x4 a2 = *(const f32x4*)(xa + kt * 32 + 8);
    f32x4 a3 = *(const f32x4*)(xa + kt * 32 + 12);
    u32x4 wv0 = *(const u32x4*)(bsrc + kt * 32);
    u32x4 wv1 = *(const u32x4*)(bsrc + kt * 32 + 8);
    u32x4 p0, p1;
    p0[0] = pk2(a0[0], a0[1]); p0[1] = pk2(a0[2], a0[3]);
    p0[2] = pk2(a1[0], a1[1]); p0[3] = pk2(a1[2], a1[3]);
    p1[0] = pk2(a2[0], a2[1]); p1[1] = pk2(a2[2], a2[3]);
    p1[2] = pk2(a3[0], a3[1]); p1[3] = pk2(a3[2], a3[3]);
    *(u32x4*)adst = p0;  *(u32x4*)(adst + 8) = p1;
    *(u32x4*)bdst = wv0; *(u32x4*)(bdst + 8) = wv1;
    __syncthreads();
    short8 af[4], bfr[4];
    #pragma unroll
    for (int mb = 0; mb < 4; ++mb)
      af[mb] = *(const short8*)(As + (wm * 64 + mb * 16 + l15) * GP + hi4 * 8);
    #pragma unroll
    for (int nb = 0; nb < 4; ++nb)
      bfr[nb] = *(const short8*)(Bs + (wn * 64 + nb * 16 + l15) * GP + hi4 * 8);
    #pragma unroll
    for (int mb = 0; mb < 4; ++mb)
      #pragma unroll
      for (int nb = 0; nb < 4; ++nb)
        acc[mb][nb] = mfma16(af[mb], bfr[nb], acc[mb][nb]);
    __syncthreads();
  }
  // epilogue: +bias, bf16, scatter into packed consumer layout
  #pragma unroll
  for (int nb = 0; nb < 4; ++nb) {
    int n = n0 + wn * 64 + nb * 16 + l15;
    int g = n >> 9, hc = n & 511, wgc = hc >> 4, lcol = hc & 15;
    float bv = bias[n];
    #pragma unroll
    for (int mb = 0; mb < 4; ++mb) {
      int mbase = m0 + wm * 64 + mb * 16 + hi4 * 4;
      #pragma unroll
      for (int i = 0; i < 4; ++i) {
        int m = mbase + i;
        int tt = m & 1023, bb = m >> 10;
        int cmt = bb >> 4, chi = (bb >> 2) & 3, cii = bb & 3;
        size_t dst = (((size_t)tt * 32 + wgc) * 4 + g) * 1024 +
                     (size_t)(chi * 16 + lcol) * 16 + cmt * 4 + cii;
        xp[dst] = f2bf(acc[mb][nb][i] + bv);
      }
    }
  }
}

// ---------------------------------------------------------------------------
// recurrence: 32 WGs x 4 waves. Wave g owns gate g for the WG's 16 h-cols,
// ALL 64 batch rows. Wh slice (16x512) in 64 VGPRs -> no spill.
// Per step: unpack prefetched xp -> chunked bypass h-loads + 64 MFMA ->
// LDS gate exchange -> B1 -> wave0: gates+publish(2KB)+flag; wave1: poll
// (broadcast-addr, s_sleep backoff) -> B2.
// ---------------------------------------------------------------------------
#define AWAIT(N) do { \
  asm volatile("s_waitcnt vmcnt(" #N ")" ::: "memory"); \
  __builtin_amdgcn_sched_barrier(0); } while (0)

// 4 bypass dwordx4 loads (one m-tile, 4 consecutive k-steps); sb uniform
#define LDMT(b0, b1, b2, b3, vof, sb, O0, O1, O2, O3) \
  asm volatile("global_load_dwordx4 %0, %4, %5 offset:" O0 " sc0 sc1\n\t" \
               "global_load_dwordx4 %1, %4, %5 offset:" O1 " sc0 sc1\n\t" \
               "global_load_dwordx4 %2, %4, %5 offset:" O2 " sc0 sc1\n\t" \
               "global_load_dwordx4 %3, %4, %5 offset:" O3 " sc0 sc1" \
               : "=v"(b0), "=v"(b1), "=v"(b2), "=v"(b3) \
               : "v"(vof), "s"(sb))

#define ISSUE(buf, sb, O0, O1, O2, O3) \
  LDMT(buf[0][0], buf[1][0], buf[2][0], buf[3][0], vA[0], sb, O0, O1, O2, O3); \
  LDMT(buf[0][1], buf[1][1], buf[2][1], buf[3][1], vA[1], sb, O0, O1, O2, O3); \
  LDMT(buf[0][2], buf[1][2], buf[2][2], buf[3][2], vA[2], sb, O0, O1, O2, O3); \
  LDMT(buf[0][3], buf[1][3], buf[2][3], buf[3][3], vA[3], sb, O0, O1, O2, O3)

#define MFMA4(buf, KB) \
  _Pragma("unroll") \
  for (int dk = 0; dk < 4; ++dk) { \
    _Pragma("unroll") \
    for (int mt = 0; mt < 4; ++mt) \
      acc[mt] = mfma16(bc(buf[dk][mt]), bw[(KB) + dk], acc[mt]); \
  }

// cached dwordx4 load via 64-bit VGPR address (divergence-safe)
#define XLD(dst, a64, O0) \
  asm volatile("global_load_dwordx4 %0, %1, off offset:" O0 \
               : "=v"(dst) : "v"(a64))

// publish one m-tile: 4 bf16 h values at rows +0..+3 (row stride 1024B)
#define ST4(vof, x0, x1, x2, x3, sb) \
  asm volatile("global_store_short %0, %1, %5 offset:0 sc0 sc1\n\t" \
               "global_store_short %0, %2, %5 offset:1024 sc0 sc1\n\t" \
               "global_store_short %0, %3, %5 offset:2048 sc0 sc1\n\t" \
               "global_store_short %0, %4, %5 offset:3072 sc0 sc1" \
               :: "v"(vof), "v"(x0), "v"(x1), "v"(x2), "v"(x3), "s"(sb) \
               : "memory")

__global__ __launch_bounds__(256, 1) void lstm_rec(
    const unsigned short* __restrict__ xp, const unsigned short* __restrict__ WhT,
    unsigned short* __restrict__ hbuf, unsigned short* __restrict__ flags,
    float* __restrict__ out)
{
  __shared__ f32x4 xch[3][4][64];   // 12KB gate exchange (i,g,o)

  int wg = blockIdx.x;
  int tid = threadIdx.x, lane = tid & 63, g = tid >> 6;
  int l15 = lane & 15, hi4 = lane >> 4;

  // Wh fragments for this wave's gate: 16 x short8 = 64 VGPR
  short8 bw[16];
  {
    const unsigned short* wsrc =
        WhT + ((size_t)wg * 64 + g * 16 + l15) * 512 + hi4 * 8;
    #pragma unroll
    for (int kk = 0; kk < 16; ++kk)
      bw[kk] = *(const short8*)(wsrc + kk * 32);
  }

  f32x4 creg[4] = {};              // cell state (updater wave only)
  unsigned int vA[4], vS[4];
  #pragma unroll
  for (int mt = 0; mt < 4; ++mt) {
    vA[mt] = (unsigned)((mt * 16 + l15) * 1024 + hi4 * 16);
    vS[mt] = (unsigned)((mt * 16 + hi4 * 4) * 1024 + (wg * 16 + l15) * 2);
  }
  unsigned int vz = 0;

  // per-lane 64-bit xp address (holds this wave's 32B/lane packet for step t)
  unsigned long long xaddr = (unsigned long long)(uintptr_t)(
      xp + ((size_t)(wg * 4 + g) * 64 + lane) * 16);

  u32x4 pc0, pc1, pn0, pn1;
  XLD(pc0, xaddr, "0");
  XLD(pc1, xaddr, "16");

  for (int t = 0; t < 1024; ++t) {
    const unsigned short* hb = hbuf + ((size_t)(t & 1) << 15);
    u32x4 avA[4][4], avB[4][4];    // [dk][mt], fully static indexing
    ISSUE(avA, hb, "0", "64", "128", "192");
    ISSUE(avB, hb, "256", "320", "384", "448");
    AWAIT(16);                      // pc + chunk A done
    f32x4 acc[4];
    #pragma unroll
    for (int mt = 0; mt < 4; ++mt)
      #pragma unroll
      for (int i = 0; i < 4; ++i) {
        int j = mt * 4 + i;
        unsigned int dw = (j < 8) ? pc0[j >> 1] : pc1[(j - 8) >> 1];
        unsigned short us = (j & 1) ? (unsigned short)(dw >> 16)
                                    : (unsigned short)(dw & 0xFFFFu);
        acc[mt][i] = bf2f(us);
      }
    MFMA4(avA, 0);
    ISSUE(avA, hb, "512", "576", "640", "704");
    if (t < 1023) xaddr += 262144ULL;   // uniform step to next t's packet
    XLD(pn0, xaddr, "0");
    XLD(pn1, xaddr, "16");
    AWAIT(16);                      // chunk B done
    MFMA4(avB, 4);
    ISSUE(avB, hb, "768", "832", "896", "960");
    AWAIT(16);                      // chunk A2 + pn done
    MFMA4(avA, 8);
    AWAIT(0);                       // chunk B2 done
    MFMA4(avB, 12);

    if (g >= 1) {                   // hand i,g,o to the updater
      #pragma unroll
      for (int mt = 0; mt < 4; ++mt)
        xch[g - 1][mt][lane] = acc[mt];
    }
    __syncthreads();                // B1

    if (g == 0) {                   // updater: gates + publish
      const unsigned short* hbn = hbuf + ((size_t)((t + 1) & 1) << 15);
      #pragma unroll
      for (int mt = 0; mt < 4; ++mt) {
        f32x4 I = xch[0][mt][lane];
        f32x4 G = xch[1][mt][lane];
        f32x4 O = xch[2][mt][lane];
        unsigned int hv[4];
        f32x4 hf;
        #pragma unroll
        for (int i = 0; i < 4; ++i) {
          float fg = sigm(acc[mt][i]);
          float ig = sigm(I[i]);
          float gg = tanh_(G[i]);
          float og = sigm(O[i]);
          float c = fg * creg[mt][i] + ig * gg;
          creg[mt][i] = c;
          float h = og * tanh_(c);
          hf[i] = h;
          hv[i] = (unsigned int)f2bf(h);
        }
        if (t < 1023) {
          ST4(vS[mt], hv[0], hv[1], hv[2], hv[3], hbn);
        } else {
          #pragma unroll
          for (int i = 0; i < 4; ++i) {
            int row = mt * 16 + hi4 * 4 + i, col = wg * 16 + l15;
            out[(size_t)row * 512 + col] = hf[i];
            out[32768 + (size_t)row * 512 + col] = creg[mt][i];
          }
        }
      }
      if (t < 1023) {
        AWAIT(0);                   // h stores at coherence point
        if (lane == 0) {
          unsigned int tv = (unsigned int)(t + 1);
          unsigned int vf = (unsigned int)(wg * 2);
          asm volatile("global_store_short %0, %1, %2 sc0 sc1"
                       :: "v"(vf), "v"(tv), "s"(flags) : "memory");
        }
      }
    } else if (g == 1 && t < 1023) {  // poller: all 32 WG flags >= t+1
      unsigned int T = (unsigned int)(t + 1);
      int spins = 0;
      for (;;) {
        u32x4 f0, f1, f2, f3;
        asm volatile("global_load_dwordx4 %0, %4, %5 offset:0 sc0 sc1\n\t"
                     "global_load_dwordx4 %1, %4, %5 offset:16 sc0 sc1\n\t"
                     "global_load_dwordx4 %2, %4, %5 offset:32 sc0 sc1\n\t"
                     "global_load_dwordx4 %3, %4, %5 offset:48 sc0 sc1"
                     : "=v"(f0), "=v"(f1), "=v"(f2), "=v"(f3)
                     : "v"(vz), "s"(flags));
        AWAIT(0);
        bool ok = true;
        #pragma unroll
        for (int j = 0; j < 4; ++j) {
          ok = ok && ((f0[j] & 0xFFFFu) >= T) && ((f0[j] >> 16) >= T);
          ok = ok && ((f1[j] & 0xFFFFu) >= T) && ((f1[j] >> 16) >= T);
          ok = ok && ((f2[j] & 0xFFFFu) >= T) && ((f2[j] >> 16) >= T);
          ok = ok && ((f3[j] & 0xFFFFu) >= T) && ((f3[j] >> 16) >= T);
        }
        if (ok) break;
        if (++spins > (1 << 16)) break;   // bounded: fail visibly, never hang
        __builtin_amdgcn_s_sleep(4);
      }
    }
    if (t < 1023) __syncthreads();  // B2: h_{t+1} globally visible
    pc0 = pn0; pc1 = pn1;
  }
}

// ---------------------------------------------------------------------------
extern "C" void kernel_launch(void* const* d_in, const int* in_sizes, int n_in,
                              void* d_out, int out_size, void* d_ws, size_t ws_size,
                              hipStream_t stream) {
  const float* x   = (const float*)d_in[0];
  const float* Wii = (const float*)d_in[1];
  const float* Whi = (const float*)d_in[2];
  const float* Wif = (const float*)d_in[3];
  const float* Whf = (const float*)d_in[4];
  const float* Wig = (const float*)d_in[5];
  const float* Whg = (const float*)d_in[6];
  const float* Wio = (const float*)d_in[7];
  const float* Who = (const float*)d_in[8];
  const float* bii = (const float*)d_in[9];
  const float* bhi = (const float*)d_in[10];
  const float* bif = (const float*)d_in[11];
  const float* bhf = (const float*)d_in[12];
  const float* big = (const float*)d_in[13];
  const float* bhg = (const float*)d_in[14];
  const float* bio = (const float*)d_in[15];
  const float* bho = (const float*)d_in[16];

  char* ws = (char*)d_ws;
  size_t off = 0;
  auto alloc = [&](size_t bytes) {
    size_t p = off; off = (off + bytes + 255) & ~(size_t)255; return p;
  };
  unsigned short* WxT  = (unsigned short*)(ws + alloc(2048UL * 512 * 2));
  unsigned short* WhT  = (unsigned short*)(ws + alloc(32UL * 64 * 512 * 2));
  float*          bias = (float*)        (ws + alloc(2048UL * 4));
  unsigned short* hbuf = (unsigned short*)(ws + alloc(2UL * 64 * 512 * 2));
  unsigned short* flags= (unsigned short*)(ws + alloc(256UL));
  unsigned short* xpb  = (unsigned short*)(ws + alloc(1024UL * 64 * 2048 * 2));
  if (off > ws_size) return;  // insufficient workspace -> fail visibly

  lstm_prep<<<2048, 256, 0, stream>>>(Wif, Wii, Wig, Wio, Whf, Whi, Whg, Who,
                                      bif, bhf, bii, bhi, big, bhg, bio, bho,
                                      WxT, WhT, bias, hbuf, flags);
  lstm_xproj<<<8192, 256, 0, stream>>>(x, WxT, bias, xpb);
  lstm_rec<<<32, 256, 0, stream>>>(xpb, WhT, hbuf, flags, (float*)d_out);
}

// Round 6
// 10116.651 us; speedup vs baseline: 1.2985x; 1.2985x over previous
//
#include <hip/hip_runtime.h>
#include <hip/hip_bf16.h>
#include <stdint.h>

typedef __attribute__((ext_vector_type(8))) short short8;
typedef __attribute__((ext_vector_type(4))) float f32x4;
typedef __attribute__((ext_vector_type(4))) unsigned int u32x4;
typedef __attribute__((ext_vector_type(2))) unsigned int u32x2;

__device__ __forceinline__ unsigned short f2bf(float x) {
  unsigned int u = __builtin_bit_cast(unsigned int, x);
  u += 0x7FFFu + ((u >> 16) & 1u);           // round-to-nearest-even
  return (unsigned short)(u >> 16);
}
__device__ __forceinline__ float bf2f(unsigned short u) {
  unsigned int v = ((unsigned int)u) << 16;
  return __builtin_bit_cast(float, v);
}
__device__ __forceinline__ unsigned int pk2(float a, float b) {
  return (unsigned int)f2bf(a) | ((unsigned int)f2bf(b) << 16);
}
__device__ __forceinline__ float sigm(float x) {
  return __builtin_amdgcn_rcpf(1.0f + __builtin_amdgcn_exp2f(-1.44269504f * x));
}
__device__ __forceinline__ float tanh_(float x) {
  return 2.0f * __builtin_amdgcn_rcpf(1.0f + __builtin_amdgcn_exp2f(-2.88539008f * x)) - 1.0f;
}
__device__ __forceinline__ f32x4 mfma16(short8 a, short8 b, f32x4 c) {
  return __builtin_amdgcn_mfma_f32_16x16x32_bf16(a, b, c, 0, 0, 0);
}
__device__ __forceinline__ short8 bc(u32x4 v) { return __builtin_bit_cast(short8, v); }

// ---------------------------------------------------------------------------
// prep: bf16 transposed weight images, fused bias, zero hbuf + flags.
// Gate order: 0=f, 1=i, 2=g, 3=o.
// WxT: [2048 n][512 k]   WhT: [32 wg][64 j][512 k]  (j = gate*16 + hc_local)
// flags: 32 ushort, one per 64B line (flag wg at byte wg*64) = 2048B.
// hbuf: 2 x [64][512] bf16 row-major.
// ---------------------------------------------------------------------------
__global__ void lstm_prep(
    const float* __restrict__ Wif, const float* __restrict__ Wii,
    const float* __restrict__ Wig, const float* __restrict__ Wio,
    const float* __restrict__ Whf, const float* __restrict__ Whi,
    const float* __restrict__ Whg, const float* __restrict__ Who,
    const float* __restrict__ bif, const float* __restrict__ bhf,
    const float* __restrict__ bii, const float* __restrict__ bhi,
    const float* __restrict__ big, const float* __restrict__ bhg,
    const float* __restrict__ bio, const float* __restrict__ bho,
    unsigned short* __restrict__ WxT, unsigned short* __restrict__ WhT,
    float* __restrict__ bias, unsigned short* __restrict__ hbuf,
    unsigned short* __restrict__ flags)
{
  const long NWX = 2048L * 512, NWH = 32L * 64 * 512;
  const long NH = 2L * 64 * 512;
  long total = NWX + NWH + 2048 + NH + 1024;   // 1024 flag ushorts (32 lines)
  for (long i = (long)blockIdx.x * blockDim.x + threadIdx.x; i < total;
       i += (long)gridDim.x * blockDim.x) {
    if (i < NWX) {
      int n = (int)(i >> 9), k = (int)(i & 511);
      int g = n >> 9, hc = n & 511;
      const float* W = (g == 0) ? Wif : (g == 1) ? Wii : (g == 2) ? Wig : Wio;
      WxT[i] = f2bf(W[k * 512 + hc]);
    } else if (i < NWX + NWH) {
      long r = i - NWX;
      int wg = (int)(r >> 15); int rest = (int)(r & 32767);
      int j = rest >> 9, k = rest & 511;
      int g = j >> 4, hc = wg * 16 + (j & 15);
      const float* W = (g == 0) ? Whf : (g == 1) ? Whi : (g == 2) ? Whg : Who;
      WhT[r] = f2bf(W[k * 512 + hc]);
    } else if (i < NWX + NWH + 2048) {
      int n = (int)(i - NWX - NWH);
      int g = n >> 9, hc = n & 511;
      const float* bi = (g == 0) ? bif : (g == 1) ? bii : (g == 2) ? big : bio;
      const float* bh = (g == 0) ? bhf : (g == 1) ? bhi : (g == 2) ? bhg : bho;
      bias[n] = bi[hc] + bh[hc];
    } else if (i < NWX + NWH + 2048 + NH) {
      hbuf[i - NWX - NWH - 2048] = 0;
    } else {
      flags[i - NWX - NWH - 2048 - NH] = 0;
    }
  }
}

// ---------------------------------------------------------------------------
// x-projection GEMM: (B*T, 512) @ (512, 2048) + bias -> bf16, written in the
// recurrent kernel's per-lane-packed layout:
//   xp[ ((t*32 + wg)*4 + g)*1024 + lane*16 + mt*4 + i ]   (ushort units)
// ---------------------------------------------------------------------------
#define GP 56  // LDS row stride (elems): 112B, 16B-aligned, 2-way banks

__global__ __launch_bounds__(256) void lstm_xproj(
    const float* __restrict__ x, const unsigned short* __restrict__ WxT,
    const float* __restrict__ bias, unsigned short* __restrict__ xp)
{
  __shared__ unsigned short As[128 * GP];
  __shared__ unsigned short Bs[128 * GP];
  int bid = blockIdx.x;
  int mt = bid & 511, nt = bid >> 9;          // 512 m-tiles, 16 n-tiles
  int m0 = mt << 7, n0 = nt << 7;
  int tid = threadIdx.x, lane = tid & 63, w = tid >> 6;
  int wm = w >> 1, wn = w & 1;
  int l15 = lane & 15, hi4 = lane >> 4;

  f32x4 acc[4][4] = {};
  int srow = tid >> 1, skq = (tid & 1) << 4;  // each thread: 1 row, 16 k
  const float* xa = x + (size_t)(m0 + srow) * 512 + skq;
  const unsigned short* bsrc = WxT + (size_t)(n0 + srow) * 512 + skq;
  unsigned short* adst = As + srow * GP + skq;
  unsigned short* bdst = Bs + srow * GP + skq;

  for (int kt = 0; kt < 16; ++kt) {
    f32x4 a0 = *(const f32x4*)(xa + kt * 32);
    f32x4 a1 = *(const f32x4*)(xa + kt * 32 + 4);
    f32x4 a2 = *(const f32x4*)(xa + kt * 32 + 8);
    f32x4 a3 = *(const f32x4*)(xa + kt * 32 + 12);
    u32x4 wv0 = *(const u32x4*)(bsrc + kt * 32);
    u32x4 wv1 = *(const u32x4*)(bsrc + kt * 32 + 8);
    u32x4 p0, p1;
    p0[0] = pk2(a0[0], a0[1]); p0[1] = pk2(a0[2], a0[3]);
    p0[2] = pk2(a1[0], a1[1]); p0[3] = pk2(a1[2], a1[3]);
    p1[0] = pk2(a2[0], a2[1]); p1[1] = pk2(a2[2], a2[3]);
    p1[2] = pk2(a3[0], a3[1]); p1[3] = pk2(a3[2], a3[3]);
    *(u32x4*)adst = p0;  *(u32x4*)(adst + 8) = p1;
    *(u32x4*)bdst = wv0; *(u32x4*)(bdst + 8) = wv1;
    __syncthreads();
    short8 af[4], bfr[4];
    #pragma unroll
    for (int mb = 0; mb < 4; ++mb)
      af[mb] = *(const short8*)(As + (wm * 64 + mb * 16 + l15) * GP + hi4 * 8);
    #pragma unroll
    for (int nb = 0; nb < 4; ++nb)
      bfr[nb] = *(const short8*)(Bs + (wn * 64 + nb * 16 + l15) * GP + hi4 * 8);
    #pragma unroll
    for (int mb = 0; mb < 4; ++mb)
      #pragma unroll
      for (int nb = 0; nb < 4; ++nb)
        acc[mb][nb] = mfma16(af[mb], bfr[nb], acc[mb][nb]);
    __syncthreads();
  }
  // epilogue: +bias, bf16, scatter into packed consumer layout
  #pragma unroll
  for (int nb = 0; nb < 4; ++nb) {
    int n = n0 + wn * 64 + nb * 16 + l15;
    int g = n >> 9, hc = n & 511, wgc = hc >> 4, lcol = hc & 15;
    float bv = bias[n];
    #pragma unroll
    for (int mb = 0; mb < 4; ++mb) {
      int mbase = m0 + wm * 64 + mb * 16 + hi4 * 4;
      #pragma unroll
      for (int i = 0; i < 4; ++i) {
        int m = mbase + i;
        int tt = m & 1023, bb = m >> 10;
        int cmt = bb >> 4, chi = (bb >> 2) & 3, cii = bb & 3;
        size_t dst = (((size_t)tt * 32 + wgc) * 4 + g) * 1024 +
                     (size_t)(chi * 16 + lcol) * 16 + cmt * 4 + cii;
        xp[dst] = f2bf(acc[mb][nb][i] + bv);
      }
    }
  }
}

// ---------------------------------------------------------------------------
// recurrence: 32 WGs x 4 waves. Wave g owns gate g (Wh slice in 64 VGPRs),
// all 64 batch rows, the WG's 16 h-cols. Per step:
//   poll(all 32 flags >= t) -> chunked sc0sc1 h-loads + 64 MFMA/wave ->
//   LDS preact dump -> B1 -> ALL 256 threads: gate math (1 row x 4 cols),
//   per-thread c-state, ONE dwordx2 h store -> drain -> B2 -> tid0 flag.
// ---------------------------------------------------------------------------
#define AWAIT(N) do { \
  asm volatile("s_waitcnt vmcnt(" #N ")" ::: "memory"); \
  __builtin_amdgcn_sched_barrier(0); } while (0)

// 4 system-coherent dwordx4 loads (one m-tile, 4 consecutive k-steps)
#define LDMT(b0, b1, b2, b3, vof, sb, O0, O1, O2, O3) \
  asm volatile("global_load_dwordx4 %0, %4, %5 offset:" O0 " sc0 sc1\n\t" \
               "global_load_dwordx4 %1, %4, %5 offset:" O1 " sc0 sc1\n\t" \
               "global_load_dwordx4 %2, %4, %5 offset:" O2 " sc0 sc1\n\t" \
               "global_load_dwordx4 %3, %4, %5 offset:" O3 " sc0 sc1" \
               : "=v"(b0), "=v"(b1), "=v"(b2), "=v"(b3) \
               : "v"(vof), "s"(sb))

#define ISSUE(buf, sb, O0, O1, O2, O3) \
  LDMT(buf[0][0], buf[1][0], buf[2][0], buf[3][0], vA[0], sb, O0, O1, O2, O3); \
  LDMT(buf[0][1], buf[1][1], buf[2][1], buf[3][1], vA[1], sb, O0, O1, O2, O3); \
  LDMT(buf[0][2], buf[1][2], buf[2][2], buf[3][2], vA[2], sb, O0, O1, O2, O3); \
  LDMT(buf[0][3], buf[1][3], buf[2][3], buf[3][3], vA[3], sb, O0, O1, O2, O3)

#define MFMA4(buf, KB) \
  _Pragma("unroll") \
  for (int dk = 0; dk < 4; ++dk) { \
    _Pragma("unroll") \
    for (int mt = 0; mt < 4; ++mt) \
      acc[mt] = mfma16(bc(buf[dk][mt]), bw[(KB) + dk], acc[mt]); \
  }

// cached dwordx4 load via 64-bit VGPR address (divergence-safe)
#define XLD(dst, a64, O0) \
  asm volatile("global_load_dwordx4 %0, %1, off offset:" O0 \
               : "=v"(dst) : "v"(a64))

__global__ __launch_bounds__(256, 1) void lstm_rec(
    const unsigned short* __restrict__ xp, const unsigned short* __restrict__ WhT,
    unsigned short* __restrict__ hbuf, unsigned short* __restrict__ flags,
    float* __restrict__ out)
{
  __shared__ float pre[4][64][17];   // padded preact exchange, 17.4 KB

  int wg = blockIdx.x;
  int tid = threadIdx.x, lane = tid & 63, g = tid >> 6;
  int l15 = lane & 15, hi4 = lane >> 4;

  // Wh fragments for this wave's gate: 16 x short8 = 64 VGPR
  short8 bw[16];
  {
    const unsigned short* wsrc =
        WhT + ((size_t)wg * 64 + g * 16 + l15) * 512 + hi4 * 8;
    #pragma unroll
    for (int kk = 0; kk < 16; ++kk)
      bw[kk] = *(const short8*)(wsrc + kk * 32);
  }

  // per-thread gate-combine coordinates: 1 row x 4 consecutive cols
  const int r = tid >> 2;                  // batch row 0..63
  const int cq = (tid & 3) * 4;            // first of 4 local cols
  float cst[4] = {0.f, 0.f, 0.f, 0.f};     // cell state (per thread)
  unsigned int vpub = (unsigned)(r * 1024 + wg * 32 + cq * 2);

  unsigned int vA[4];
  #pragma unroll
  for (int mt = 0; mt < 4; ++mt)
    vA[mt] = (unsigned)((mt * 16 + l15) * 1024 + hi4 * 16);

  // per-lane 64-bit xp address (this wave's 32B/lane packet for step t)
  unsigned long long xaddr = (unsigned long long)(uintptr_t)(
      xp + ((size_t)(wg * 4 + g) * 64 + lane) * 16);
  // per-lane flag-line address (flag w at byte w*64)
  unsigned long long faddr = (unsigned long long)(uintptr_t)(
      (const char*)flags + (size_t)(lane & 31) * 64);

  u32x4 pc0, pc1, pn0, pn1;
  XLD(pc0, xaddr, "0");
  XLD(pc1, xaddr, "16");

  for (int t = 0; t < 1024; ++t) {
    // ---- poll: all 32 WGs have published h_t (and finished reading t-1) ----
    {
      unsigned int T = (unsigned)t;
      int spins = 0;
      for (;;) {
        unsigned int fv;
        asm volatile("global_load_ushort %0, %1, off sc0 sc1"
                     : "=v"(fv) : "v"(faddr));
        AWAIT(0);
        if (__all((int)(fv >= T))) break;
        if (++spins > (1 << 17)) break;   // bounded: fail visibly, never hang
      }
    }
    // ---- h-loads (system scope) pipelined under MFMA; R4-proven ledger ----
    const unsigned short* hb = hbuf + ((size_t)(t & 1) << 15);
    u32x4 avA[4][4], avB[4][4];    // [dk][mt], fully static indexing
    ISSUE(avA, hb, "0", "64", "128", "192");
    ISSUE(avB, hb, "256", "320", "384", "448");
    AWAIT(16);                      // chunk A done
    f32x4 acc[4];
    #pragma unroll
    for (int mt = 0; mt < 4; ++mt)
      #pragma unroll
      for (int i = 0; i < 4; ++i) {
        int j = mt * 4 + i;
        unsigned int dw = (j < 8) ? pc0[j >> 1] : pc1[(j - 8) >> 1];
        unsigned short us = (j & 1) ? (unsigned short)(dw >> 16)
                                    : (unsigned short)(dw & 0xFFFFu);
        acc[mt][i] = bf2f(us);
      }
    MFMA4(avA, 0);
    ISSUE(avA, hb, "512", "576", "640", "704");
    if (t < 1023) xaddr += 262144ULL;   // uniform step to next t's packet
    XLD(pn0, xaddr, "0");
    XLD(pn1, xaddr, "16");
    AWAIT(16);                      // chunk B done
    MFMA4(avB, 4);
    ISSUE(avB, hb, "768", "832", "896", "960");
    AWAIT(16);                      // chunk A2 + pn done
    MFMA4(avA, 8);
    AWAIT(0);                       // chunk B2 done
    MFMA4(avB, 12);

    // ---- dump preacts to LDS (wave g owns plane g) ----
    #pragma unroll
    for (int mt = 0; mt < 4; ++mt)
      #pragma unroll
      for (int i = 0; i < 4; ++i)
        pre[g][mt * 16 + hi4 * 4 + i][l15] = acc[mt][i];
    __syncthreads();                // B1

    // ---- all-thread gate combine: row r, cols cq..cq+3 ----
    float hv[4];
    #pragma unroll
    for (int i = 0; i < 4; ++i) {
      float fg = sigm(pre[0][r][cq + i]);
      float ig = sigm(pre[1][r][cq + i]);
      float gg = tanh_(pre[2][r][cq + i]);
      float og = sigm(pre[3][r][cq + i]);
      float c = fg * cst[i] + ig * gg;
      cst[i] = c;
      hv[i] = og * tanh_(c);
    }
    if (t < 1023) {
      const unsigned short* hbn = hbuf + ((size_t)((t + 1) & 1) << 15);
      u32x2 pk; pk[0] = pk2(hv[0], hv[1]); pk[1] = pk2(hv[2], hv[3]);
      asm volatile("global_store_dwordx2 %0, %1, %2 sc0 sc1"
                   :: "v"(vpub), "v"(pk), "s"(hbn) : "memory");
      AWAIT(0);                     // h store at coherence point
      __syncthreads();              // B2: whole WG's h_{t+1} committed
      if (tid == 0) {
        unsigned int tv = (unsigned int)(t + 1);
        unsigned int vf = (unsigned int)(wg * 64);   // our 64B line
        asm volatile("global_store_short %0, %1, %2 sc0 sc1"
                     :: "v"(vf), "v"(tv), "s"(flags) : "memory");
      }
    } else {
      // final step: write h and c (fp32) straight to out
      f32x4 ho, co;
      #pragma unroll
      for (int i = 0; i < 4; ++i) { ho[i] = hv[i]; co[i] = cst[i]; }
      *(f32x4*)(out + (size_t)r * 512 + wg * 16 + cq) = ho;
      *(f32x4*)(out + 32768 + (size_t)r * 512 + wg * 16 + cq) = co;
    }
    pc0 = pn0; pc1 = pn1;
  }
}

// ---------------------------------------------------------------------------
extern "C" void kernel_launch(void* const* d_in, const int* in_sizes, int n_in,
                              void* d_out, int out_size, void* d_ws, size_t ws_size,
                              hipStream_t stream) {
  const float* x   = (const float*)d_in[0];
  const float* Wii = (const float*)d_in[1];
  const float* Whi = (const float*)d_in[2];
  const float* Wif = (const float*)d_in[3];
  const float* Whf = (const float*)d_in[4];
  const float* Wig = (const float*)d_in[5];
  const float* Whg = (const float*)d_in[6];
  const float* Wio = (const float*)d_in[7];
  const float* Who = (const float*)d_in[8];
  const float* bii = (const float*)d_in[9];
  const float* bhi = (const float*)d_in[10];
  const float* bif = (const float*)d_in[11];
  const float* bhf = (const float*)d_in[12];
  const float* big = (const float*)d_in[13];
  const float* bhg = (const float*)d_in[14];
  const float* bio = (const float*)d_in[15];
  const float* bho = (const float*)d_in[16];

  char* ws = (char*)d_ws;
  size_t off = 0;
  auto alloc = [&](size_t bytes) {
    size_t p = off; off = (off + bytes + 255) & ~(size_t)255; return p;
  };
  unsigned short* WxT  = (unsigned short*)(ws + alloc(2048UL * 512 * 2));
  unsigned short* WhT  = (unsigned short*)(ws + alloc(32UL * 64 * 512 * 2));
  float*          bias = (float*)        (ws + alloc(2048UL * 4));
  unsigned short* hbuf = (unsigned short*)(ws + alloc(2UL * 64 * 512 * 2));
  unsigned short* flags= (unsigned short*)(ws + alloc(2048UL));
  unsigned short* xpb  = (unsigned short*)(ws + alloc(1024UL * 64 * 2048 * 2));
  if (off > ws_size) return;  // insufficient workspace -> fail visibly

  lstm_prep<<<2048, 256, 0, stream>>>(Wif, Wii, Wig, Wio, Whf, Whi, Whg, Who,
                                      bif, bhf, bii, bhi, big, bhg, bio, bho,
                                      WxT, WhT, bias, hbuf, flags);
  lstm_xproj<<<8192, 256, 0, stream>>>(x, WxT, bias, xpb);
  lstm_rec<<<32, 256, 0, stream>>>(xpb, WhT, hbuf, flags, (float*)d_out);
}

// Round 7
// 6182.618 us; speedup vs baseline: 2.1248x; 1.6363x over previous
//
#include <hip/hip_runtime.h>
#include <hip/hip_bf16.h>
#include <stdint.h>

typedef __attribute__((ext_vector_type(8))) short short8;
typedef __attribute__((ext_vector_type(4))) float f32x4;
typedef __attribute__((ext_vector_type(4))) unsigned int u32x4;
typedef __attribute__((ext_vector_type(2))) unsigned int u32x2;

__device__ __forceinline__ unsigned short f2bf(float x) {
  unsigned int u = __builtin_bit_cast(unsigned int, x);
  u += 0x7FFFu + ((u >> 16) & 1u);           // round-to-nearest-even
  return (unsigned short)(u >> 16);
}
__device__ __forceinline__ float bf2f(unsigned short u) {
  unsigned int v = ((unsigned int)u) << 16;
  return __builtin_bit_cast(float, v);
}
__device__ __forceinline__ unsigned int pk2(float a, float b) {
  return (unsigned int)f2bf(a) | ((unsigned int)f2bf(b) << 16);
}
__device__ __forceinline__ float sigm(float x) {
  return __builtin_amdgcn_rcpf(1.0f + __builtin_amdgcn_exp2f(-1.44269504f * x));
}
__device__ __forceinline__ float tanh_(float x) {
  return 2.0f * __builtin_amdgcn_rcpf(1.0f + __builtin_amdgcn_exp2f(-2.88539008f * x)) - 1.0f;
}
__device__ __forceinline__ f32x4 mfma16(short8 a, short8 b, f32x4 c) {
  return __builtin_amdgcn_mfma_f32_16x16x32_bf16(a, b, c, 0, 0, 0);
}
__device__ __forceinline__ short8 bc(u32x4 v) { return __builtin_bit_cast(short8, v); }

// ---------------------------------------------------------------------------
// prep: bf16 transposed weight images, fused bias, init h ring.
// Gate order: 0=f, 1=i, 2=g, 3=o.
// WxT: [2048 n][512 k]   WhT: [32 wg][64 j][512 k]  (j = gate*16 + hc_local)
// h ring: 4 slots x [64][512] bf16. Slot 0 = h_0 = +0.0 (fresh);
// slots 1..3 = 0x8000 poison (bf16 -0.0, never produced: producers cleanse).
// ---------------------------------------------------------------------------
__global__ void lstm_prep(
    const float* __restrict__ Wif, const float* __restrict__ Wii,
    const float* __restrict__ Wig, const float* __restrict__ Wio,
    const float* __restrict__ Whf, const float* __restrict__ Whi,
    const float* __restrict__ Whg, const float* __restrict__ Who,
    const float* __restrict__ bif, const float* __restrict__ bhf,
    const float* __restrict__ bii, const float* __restrict__ bhi,
    const float* __restrict__ big, const float* __restrict__ bhg,
    const float* __restrict__ bio, const float* __restrict__ bho,
    unsigned short* __restrict__ WxT, unsigned short* __restrict__ WhT,
    float* __restrict__ bias, unsigned short* __restrict__ hring)
{
  const long NWX = 2048L * 512, NWH = 32L * 64 * 512;
  const long NR = 4L * 64 * 512;               // ring: 131072 ushorts
  long total = NWX + NWH + 2048 + NR;
  for (long i = (long)blockIdx.x * blockDim.x + threadIdx.x; i < total;
       i += (long)gridDim.x * blockDim.x) {
    if (i < NWX) {
      int n = (int)(i >> 9), k = (int)(i & 511);
      int g = n >> 9, hc = n & 511;
      const float* W = (g == 0) ? Wif : (g == 1) ? Wii : (g == 2) ? Wig : Wio;
      WxT[i] = f2bf(W[k * 512 + hc]);
    } else if (i < NWX + NWH) {
      long r = i - NWX;
      int wg = (int)(r >> 15); int rest = (int)(r & 32767);
      int j = rest >> 9, k = rest & 511;
      int g = j >> 4, hc = wg * 16 + (j & 15);
      const float* W = (g == 0) ? Whf : (g == 1) ? Whi : (g == 2) ? Whg : Who;
      WhT[r] = f2bf(W[k * 512 + hc]);
    } else if (i < NWX + NWH + 2048) {
      int n = (int)(i - NWX - NWH);
      int g = n >> 9, hc = n & 511;
      const float* bi = (g == 0) ? bif : (g == 1) ? bii : (g == 2) ? big : bio;
      const float* bh = (g == 0) ? bhf : (g == 1) ? bhi : (g == 2) ? bhg : bho;
      bias[n] = bi[hc] + bh[hc];
    } else {
      long r = i - NWX - NWH - 2048;
      hring[r] = (r < 32768) ? (unsigned short)0 : (unsigned short)0x8000u;
    }
  }
}

// ---------------------------------------------------------------------------
// x-projection GEMM: (B*T, 512) @ (512, 2048) + bias -> bf16, written in the
// recurrent kernel's per-lane-packed layout for the 2x2 wave split:
//   xp[ ((t*32 + wg)*4 + (mw*2+gw))*1024 + (hi*16+lcol)*16 + (mt*2+gs)*4 + i ]
// ---------------------------------------------------------------------------
#define GP 56  // LDS row stride (elems): 112B, 16B-aligned, 2-way banks

__global__ __launch_bounds__(256) void lstm_xproj(
    const float* __restrict__ x, const unsigned short* __restrict__ WxT,
    const float* __restrict__ bias, unsigned short* __restrict__ xp)
{
  __shared__ unsigned short As[128 * GP];
  __shared__ unsigned short Bs[128 * GP];
  int bid = blockIdx.x;
  int mt = bid & 511, nt = bid >> 9;          // 512 m-tiles, 16 n-tiles
  int m0 = mt << 7, n0 = nt << 7;
  int tid = threadIdx.x, lane = tid & 63, w = tid >> 6;
  int wm = w >> 1, wn = w & 1;
  int l15 = lane & 15, hi4 = lane >> 4;

  f32x4 acc[4][4] = {};
  int srow = tid >> 1, skq = (tid & 1) << 4;  // each thread: 1 row, 16 k
  const float* xa = x + (size_t)(m0 + srow) * 512 + skq;
  const unsigned short* bsrc = WxT + (size_t)(n0 + srow) * 512 + skq;
  unsigned short* adst = As + srow * GP + skq;
  unsigned short* bdst = Bs + srow * GP + skq;

  for (int kt = 0; kt < 16; ++kt) {
    f32x4 a0 = *(const f32x4*)(xa + kt * 32);
    f32x4 a1 = *(const f32x4*)(xa + kt * 32 + 4);
    f32x4 a2 = *(const f32x4*)(xa + kt * 32 + 8);
    f32x4 a3 = *(const f32x4*)(xa + kt * 32 + 12);
    u32x4 wv0 = *(const u32x4*)(bsrc + kt * 32);
    u32x4 wv1 = *(const u32x4*)(bsrc + kt * 32 + 8);
    u32x4 p0, p1;
    p0[0] = pk2(a0[0], a0[1]); p0[1] = pk2(a0[2], a0[3]);
    p0[2] = pk2(a1[0], a1[1]); p0[3] = pk2(a1[2], a1[3]);
    p1[0] = pk2(a2[0], a2[1]); p1[1] = pk2(a2[2], a2[3]);
    p1[2] = pk2(a3[0], a3[1]); p1[3] = pk2(a3[2], a3[3]);
    *(u32x4*)adst = p0;  *(u32x4*)(adst + 8) = p1;
    *(u32x4*)bdst = wv0; *(u32x4*)(bdst + 8) = wv1;
    __syncthreads();
    short8 af[4], bfr[4];
    #pragma unroll
    for (int mb = 0; mb < 4; ++mb)
      af[mb] = *(const short8*)(As + (wm * 64 + mb * 16 + l15) * GP + hi4 * 8);
    #pragma unroll
    for (int nb = 0; nb < 4; ++nb)
      bfr[nb] = *(const short8*)(Bs + (wn * 64 + nb * 16 + l15) * GP + hi4 * 8);
    #pragma unroll
    for (int mb = 0; mb < 4; ++mb)
      #pragma unroll
      for (int nb = 0; nb < 4; ++nb)
        acc[mb][nb] = mfma16(af[mb], bfr[nb], acc[mb][nb]);
    __syncthreads();
  }
  // epilogue: +bias, bf16, scatter into packed consumer layout (2x2 split)
  #pragma unroll
  for (int nb = 0; nb < 4; ++nb) {
    int n = n0 + wn * 64 + nb * 16 + l15;
    int gate = n >> 9, hc = n & 511, wgc = hc >> 4, lcol = hc & 15;
    int gw2 = gate >> 1, gs2 = gate & 1;
    float bv = bias[n];
    #pragma unroll
    for (int mb = 0; mb < 4; ++mb) {
      int mbase = m0 + wm * 64 + mb * 16 + hi4 * 4;
      #pragma unroll
      for (int i = 0; i < 4; ++i) {
        int m = mbase + i;
        int tt = m & 1023, bb = m >> 10;
        int mwc = bb >> 5, mtc = (bb >> 4) & 1, chi = (bb >> 2) & 3, cii = bb & 3;
        size_t dst = (((size_t)tt * 32 + wgc) * 4 + (mwc * 2 + gw2)) * 1024 +
                     (size_t)(chi * 16 + lcol) * 16 + (mtc * 2 + gs2) * 4 + cii;
        xp[dst] = f2bf(acc[mb][nb][i] + bv);
      }
    }
  }
}

// ---------------------------------------------------------------------------
// recurrence: 32 WGs x 4 waves. Wave w = (mw = w>>1, gw = w&1): rows
// [mw*32, mw*32+32), gates {2gw, 2gw+1}; Wh pair in 128 VGPRs. Per step:
//   sentinel-poll 16 granules/thread (sc0sc1) from ring slot t%4 ->
//   ds_write staged h to XOR-swizzled LDS -> re-poison slot (t-2)%4 ->
//   B1 -> MFMA from LDS + reg Wh -> preact dump -> B2 ->
//   all-thread gate combine -> AWAIT(0) -> cleansed publish to slot (t+1)%4.
// One coherence hop per step; no flags, no fences.
// ---------------------------------------------------------------------------
#define AWAIT(N) do { \
  asm volatile("s_waitcnt vmcnt(" #N ")" ::: "memory"); \
  __builtin_amdgcn_sched_barrier(0); } while (0)

// 4 system-scope dwordx4 loads, per-load VGPR voffset + uniform SGPR base
#define PLD4(d0, d1, d2, d3, v0, v1, v2, v3, sb) \
  asm volatile("global_load_dwordx4 %0, %4, %8 sc0 sc1\n\t" \
               "global_load_dwordx4 %1, %5, %8 sc0 sc1\n\t" \
               "global_load_dwordx4 %2, %6, %8 sc0 sc1\n\t" \
               "global_load_dwordx4 %3, %7, %8 sc0 sc1" \
               : "=v"(d0), "=v"(d1), "=v"(d2), "=v"(d3) \
               : "v"(v0), "v"(v1), "v"(v2), "v"(v3), "s"(sb))

// cached dwordx4 load via 64-bit VGPR address (divergence-safe)
#define XLD(dst, a64, O0) \
  asm volatile("global_load_dwordx4 %0, %1, off offset:" O0 \
               : "=v"(dst) : "v"(a64))

__global__ __launch_bounds__(256, 1) void lstm_rec(
    const unsigned short* __restrict__ xp, const unsigned short* __restrict__ WhT,
    unsigned short* __restrict__ hring, float* __restrict__ out)
{
  __shared__ unsigned short hA[32768];   // 64 KB staged h (XOR-swizzled)
  __shared__ float pre[4][64][17];       // 17.4 KB preact exchange

  int wg = blockIdx.x;
  int tid = threadIdx.x, lane = tid & 63, w = tid >> 6;
  int mw = w >> 1, gw = w & 1;
  int l15 = lane & 15, hi4 = lane >> 4;

  // Wh fragments for this wave's 2 gates: 2 x 16 x short8 = 128 VGPR
  short8 bw[2][16];
  #pragma unroll
  for (int gs = 0; gs < 2; ++gs) {
    const unsigned short* wsrc =
        WhT + ((size_t)wg * 64 + (gw * 2 + gs) * 16 + l15) * 512 + hi4 * 8;
    #pragma unroll
    for (int kk = 0; kk < 16; ++kk)
      bw[gs][kk] = *(const short8*)(wsrc + kk * 32);
  }

  // poll voffsets: thread's 16 granules at gid = k*256 + tid (byte = gid*16)
  unsigned int voff[16];
  #pragma unroll
  for (int k = 0; k < 16; ++k)
    voff[k] = (unsigned)(tid * 16 + k * 4096);

  // gate-combine coordinates: 1 row x 4 consecutive local cols
  const int r = tid >> 2;
  const int cq = (tid & 3) * 4;
  float cst[4] = {0.f, 0.f, 0.f, 0.f};
  unsigned int vpub = (unsigned)(r * 1024 + (wg * 16 + cq) * 2);

  // per-lane 64-bit xp address (this wave's 32B/lane packet for step t)
  unsigned long long xaddr = (unsigned long long)(uintptr_t)(
      xp + ((size_t)(wg * 4 + w) * 64 + lane) * 16);

  u32x4 pc0, pc1, pn0, pn1;
  XLD(pc0, xaddr, "0");
  XLD(pc1, xaddr, "16");

  for (int t = 0; t < 1024; ++t) {
    const unsigned short* hb = hring + ((size_t)(t & 3) << 15);
    // ---- sentinel poll: loop until all 16 granules are fully non-poison ----
    u32x4 gb[16];
    {
      int spins = 0;
      for (;;) {
        PLD4(gb[0], gb[1], gb[2], gb[3], voff[0], voff[1], voff[2], voff[3], hb);
        PLD4(gb[4], gb[5], gb[6], gb[7], voff[4], voff[5], voff[6], voff[7], hb);
        PLD4(gb[8], gb[9], gb[10], gb[11], voff[8], voff[9], voff[10], voff[11], hb);
        PLD4(gb[12], gb[13], gb[14], gb[15], voff[12], voff[13], voff[14], voff[15], hb);
        AWAIT(0);
        bool ok = true;
        #pragma unroll
        for (int k = 0; k < 16; ++k)
          #pragma unroll
          for (int j = 0; j < 4; ++j) {
            unsigned int v = gb[k][j];
            ok = ok && ((v & 0xFFFFu) != 0x8000u) && ((v >> 16) != 0x8000u);
          }
        if (__all((int)ok)) break;
        if (++spins > (1 << 15)) break;   // bounded: fail visibly, never hang
      }
    }
    // ---- stage to LDS (row = k*4 + w, contiguous per wave, XOR swizzle) ----
    #pragma unroll
    for (int k = 0; k < 16; ++k) {
      int row = k * 4 + w;
      int byt = (row * 1024 + lane * 16) ^ ((row & 7) << 4);
      *(u32x4*)((char*)hA + byt) = gb[k];
    }
    // ---- re-poison slot (t-2)%4 (own produced slice; drained before publish)
    if (t >= 2) {
      const unsigned short* hp = hring + ((size_t)((t - 2) & 3) << 15);
      u32x2 pv; pv[0] = 0x80008000u; pv[1] = 0x80008000u;
      asm volatile("global_store_dwordx2 %0, %1, %2 sc0 sc1"
                   :: "v"(vpub), "v"(pv), "s"(hp) : "memory");
    }
    __syncthreads();                // B1: staged h_t visible in LDS

    // ---- acc init from prefetched xp ----
    f32x4 acc[2][2];
    #pragma unroll
    for (int mt = 0; mt < 2; ++mt)
      #pragma unroll
      for (int gs = 0; gs < 2; ++gs)
        #pragma unroll
        for (int i = 0; i < 4; ++i) {
          int j = (mt * 2 + gs) * 4 + i;
          unsigned int dw = (j < 8) ? pc0[j >> 1] : pc1[(j - 8) >> 1];
          unsigned short us = (j & 1) ? (unsigned short)(dw >> 16)
                                      : (unsigned short)(dw & 0xFFFFu);
          acc[mt][gs][i] = bf2f(us);
        }
    // prefetch next step's xp
    if (t < 1023) xaddr += 262144ULL;
    XLD(pn0, xaddr, "0");
    XLD(pn1, xaddr, "16");

    // ---- MFMA: a-frags from swizzled LDS, b-frags from regs ----
    #pragma unroll
    for (int kk = 0; kk < 16; ++kk) {
      int r0 = mw * 32 + l15;
      int r1 = r0 + 16;
      int b0 = (r0 * 1024 + kk * 64 + hi4 * 16) ^ ((r0 & 7) << 4);
      int b1 = (r1 * 1024 + kk * 64 + hi4 * 16) ^ ((r1 & 7) << 4);
      short8 a0 = *(const short8*)((const char*)hA + b0);
      short8 a1 = *(const short8*)((const char*)hA + b1);
      acc[0][0] = mfma16(a0, bw[0][kk], acc[0][0]);
      acc[0][1] = mfma16(a0, bw[1][kk], acc[0][1]);
      acc[1][0] = mfma16(a1, bw[0][kk], acc[1][0]);
      acc[1][1] = mfma16(a1, bw[1][kk], acc[1][1]);
    }

    // ---- preact dump ----
    #pragma unroll
    for (int mt = 0; mt < 2; ++mt)
      #pragma unroll
      for (int gs = 0; gs < 2; ++gs)
        #pragma unroll
        for (int i = 0; i < 4; ++i)
          pre[gw * 2 + gs][mw * 32 + mt * 16 + hi4 * 4 + i][l15] = acc[mt][gs][i];
    __syncthreads();                // B2

    // ---- all-thread gate combine: row r, local cols cq..cq+3 ----
    float hv[4];
    #pragma unroll
    for (int i = 0; i < 4; ++i) {
      float fg = sigm(pre[0][r][cq + i]);
      float ig = sigm(pre[1][r][cq + i]);
      float gg = tanh_(pre[2][r][cq + i]);
      float og = sigm(pre[3][r][cq + i]);
      float c = fg * cst[i] + ig * gg;
      cst[i] = c;
      hv[i] = og * tanh_(c);
    }
    if (t < 1023) {
      AWAIT(0);                     // drain re-poison (+pn, publish backlog)
      const unsigned short* hbn = hring + ((size_t)((t + 1) & 3) << 15);
      unsigned int u[4];
      #pragma unroll
      for (int i = 0; i < 4; ++i) {
        unsigned int us = f2bf(hv[i]);
        u[i] = (us == 0x8000u) ? 0u : us;   // cleanse -0.0 (poison)
      }
      u32x2 pk; pk[0] = u[0] | (u[1] << 16); pk[1] = u[2] | (u[3] << 16);
      asm volatile("global_store_dwordx2 %0, %1, %2 sc0 sc1"
                   :: "v"(vpub), "v"(pk), "s"(hbn) : "memory");
    } else {
      f32x4 ho, co;
      #pragma unroll
      for (int i = 0; i < 4; ++i) { ho[i] = hv[i]; co[i] = cst[i]; }
      *(f32x4*)(out + (size_t)r * 512 + wg * 16 + cq) = ho;
      *(f32x4*)(out + 32768 + (size_t)r * 512 + wg * 16 + cq) = co;
    }
    pc0 = pn0; pc1 = pn1;
  }
}

// ---------------------------------------------------------------------------
extern "C" void kernel_launch(void* const* d_in, const int* in_sizes, int n_in,
                              void* d_out, int out_size, void* d_ws, size_t ws_size,
                              hipStream_t stream) {
  const float* x   = (const float*)d_in[0];
  const float* Wii = (const float*)d_in[1];
  const float* Whi = (const float*)d_in[2];
  const float* Wif = (const float*)d_in[3];
  const float* Whf = (const float*)d_in[4];
  const float* Wig = (const float*)d_in[5];
  const float* Whg = (const float*)d_in[6];
  const float* Wio = (const float*)d_in[7];
  const float* Who = (const float*)d_in[8];
  const float* bii = (const float*)d_in[9];
  const float* bhi = (const float*)d_in[10];
  const float* bif = (const float*)d_in[11];
  const float* bhf = (const float*)d_in[12];
  const float* big = (const float*)d_in[13];
  const float* bhg = (const float*)d_in[14];
  const float* bio = (const float*)d_in[15];
  const float* bho = (const float*)d_in[16];

  char* ws = (char*)d_ws;
  size_t off = 0;
  auto alloc = [&](size_t bytes) {
    size_t p = off; off = (off + bytes + 255) & ~(size_t)255; return p;
  };
  unsigned short* WxT  = (unsigned short*)(ws + alloc(2048UL * 512 * 2));
  unsigned short* WhT  = (unsigned short*)(ws + alloc(32UL * 64 * 512 * 2));
  float*          bias = (float*)        (ws + alloc(2048UL * 4));
  unsigned short* hring= (unsigned short*)(ws + alloc(4UL * 64 * 512 * 2));
  unsigned short* xpb  = (unsigned short*)(ws + alloc(1024UL * 64 * 2048 * 2));
  if (off > ws_size) return;  // insufficient workspace -> fail visibly

  lstm_prep<<<2048, 256, 0, stream>>>(Wif, Wii, Wig, Wio, Whf, Whi, Whg, Who,
                                      bif, bhf, bii, bhi, big, bhg, bio, bho,
                                      WxT, WhT, bias, hring);
  lstm_xproj<<<8192, 256, 0, stream>>>(x, WxT, bias, xpb);
  lstm_rec<<<32, 256, 0, stream>>>(xpb, WhT, hring, (float*)d_out);
}

// Round 8
// 4013.543 us; speedup vs baseline: 3.2731x; 1.5404x over previous
//
#include <hip/hip_runtime.h>
#include <hip/hip_bf16.h>
#include <stdint.h>

typedef __attribute__((ext_vector_type(8))) short short8;
typedef __attribute__((ext_vector_type(4))) float f32x4;
typedef __attribute__((ext_vector_type(4))) unsigned int u32x4;
typedef __attribute__((ext_vector_type(2))) unsigned int u32x2;

__device__ __forceinline__ unsigned short f2bf(float x) {
  unsigned int u = __builtin_bit_cast(unsigned int, x);
  u += 0x7FFFu + ((u >> 16) & 1u);           // round-to-nearest-even
  return (unsigned short)(u >> 16);
}
__device__ __forceinline__ float bf2f(unsigned short u) {
  unsigned int v = ((unsigned int)u) << 16;
  return __builtin_bit_cast(float, v);
}
__device__ __forceinline__ unsigned int pk2(float a, float b) {
  return (unsigned int)f2bf(a) | ((unsigned int)f2bf(b) << 16);
}
__device__ __forceinline__ float sigm(float x) {
  return __builtin_amdgcn_rcpf(1.0f + __builtin_amdgcn_exp2f(-1.44269504f * x));
}
__device__ __forceinline__ float tanh_(float x) {
  return 2.0f * __builtin_amdgcn_rcpf(1.0f + __builtin_amdgcn_exp2f(-2.88539008f * x)) - 1.0f;
}
__device__ __forceinline__ f32x4 mfma16(short8 a, short8 b, f32x4 c) {
  return __builtin_amdgcn_mfma_f32_16x16x32_bf16(a, b, c, 0, 0, 0);
}
__device__ __forceinline__ short8 bc(u32x4 v) { return __builtin_bit_cast(short8, v); }

// ---------------------------------------------------------------------------
// prep: bf16 transposed weight images, fused bias, init 2-domain h ring.
// Gate order: 0=f, 1=i, 2=g, 3=o.
// WxT: [2048 n][512 k]   WhT: [32 wgl][64 j][512 k]  (j = gate*16 + hc_local)
// h ring: 2 domains x 4 slots x [32 rows][512 cols] bf16.
// Per domain: slot 0 = h_0 = +0.0 (fresh); slots 1..3 = 0x8000 poison
// (bf16 -0.0, never produced: producers cleanse -0.0 -> +0.0).
// ---------------------------------------------------------------------------
__global__ void lstm_prep(
    const float* __restrict__ Wif, const float* __restrict__ Wii,
    const float* __restrict__ Wig, const float* __restrict__ Wio,
    const float* __restrict__ Whf, const float* __restrict__ Whi,
    const float* __restrict__ Whg, const float* __restrict__ Who,
    const float* __restrict__ bif, const float* __restrict__ bhf,
    const float* __restrict__ bii, const float* __restrict__ bhi,
    const float* __restrict__ big, const float* __restrict__ bhg,
    const float* __restrict__ bio, const float* __restrict__ bho,
    unsigned short* __restrict__ WxT, unsigned short* __restrict__ WhT,
    float* __restrict__ bias, unsigned short* __restrict__ hring)
{
  const long NWX = 2048L * 512, NWH = 32L * 64 * 512;
  const long NR = 2L * 4 * 32 * 512;           // ring: 131072 ushorts
  long total = NWX + NWH + 2048 + NR;
  for (long i = (long)blockIdx.x * blockDim.x + threadIdx.x; i < total;
       i += (long)gridDim.x * blockDim.x) {
    if (i < NWX) {
      int n = (int)(i >> 9), k = (int)(i & 511);
      int g = n >> 9, hc = n & 511;
      const float* W = (g == 0) ? Wif : (g == 1) ? Wii : (g == 2) ? Wig : Wio;
      WxT[i] = f2bf(W[k * 512 + hc]);
    } else if (i < NWX + NWH) {
      long r = i - NWX;
      int wg = (int)(r >> 15); int rest = (int)(r & 32767);
      int j = rest >> 9, k = rest & 511;
      int g = j >> 4, hc = wg * 16 + (j & 15);
      const float* W = (g == 0) ? Whf : (g == 1) ? Whi : (g == 2) ? Whg : Who;
      WhT[r] = f2bf(W[k * 512 + hc]);
    } else if (i < NWX + NWH + 2048) {
      int n = (int)(i - NWX - NWH);
      int g = n >> 9, hc = n & 511;
      const float* bi = (g == 0) ? bif : (g == 1) ? bii : (g == 2) ? big : bio;
      const float* bh = (g == 0) ? bhf : (g == 1) ? bhi : (g == 2) ? bhg : bho;
      bias[n] = bi[hc] + bh[hc];
    } else {
      long r = i - NWX - NWH - 2048;
      long rr = r & 65535;                     // within-domain index
      hring[r] = (rr < 16384) ? (unsigned short)0 : (unsigned short)0x8000u;
    }
  }
}

// ---------------------------------------------------------------------------
// x-projection GEMM: (B*T, 512) @ (512, 2048) + bias -> bf16, written in the
// recurrent kernel's per-lane-packed layout (2-domain, 2x2 wave split):
//   dst = (((t*64 + d*32+wgl)*4 + (mw*2+gw))*64 + (chi*16+lcol))*8 + gs*4+cii
// ---------------------------------------------------------------------------
#define GP 56  // LDS row stride (elems): 112B, 16B-aligned, 2-way banks

__global__ __launch_bounds__(256) void lstm_xproj(
    const float* __restrict__ x, const unsigned short* __restrict__ WxT,
    const float* __restrict__ bias, unsigned short* __restrict__ xp)
{
  __shared__ unsigned short As[128 * GP];
  __shared__ unsigned short Bs[128 * GP];
  int bid = blockIdx.x;
  int mt = bid & 511, nt = bid >> 9;          // 512 m-tiles, 16 n-tiles
  int m0 = mt << 7, n0 = nt << 7;
  int tid = threadIdx.x, lane = tid & 63, w = tid >> 6;
  int wm = w >> 1, wn = w & 1;
  int l15 = lane & 15, hi4 = lane >> 4;

  f32x4 acc[4][4] = {};
  int srow = tid >> 1, skq = (tid & 1) << 4;  // each thread: 1 row, 16 k
  const float* xa = x + (size_t)(m0 + srow) * 512 + skq;
  const unsigned short* bsrc = WxT + (size_t)(n0 + srow) * 512 + skq;
  unsigned short* adst = As + srow * GP + skq;
  unsigned short* bdst = Bs + srow * GP + skq;

  for (int kt = 0; kt < 16; ++kt) {
    f32x4 a0 = *(const f32x4*)(xa + kt * 32);
    f32x4 a1 = *(const f32x4*)(xa + kt * 32 + 4);
    f32x4 a2 = *(const f32x4*)(xa + kt * 32 + 8);
    f32x4 a3 = *(const f32x4*)(xa + kt * 32 + 12);
    u32x4 wv0 = *(const u32x4*)(bsrc + kt * 32);
    u32x4 wv1 = *(const u32x4*)(bsrc + kt * 32 + 8);
    u32x4 p0, p1;
    p0[0] = pk2(a0[0], a0[1]); p0[1] = pk2(a0[2], a0[3]);
    p0[2] = pk2(a1[0], a1[1]); p0[3] = pk2(a1[2], a1[3]);
    p1[0] = pk2(a2[0], a2[1]); p1[1] = pk2(a2[2], a2[3]);
    p1[2] = pk2(a3[0], a3[1]); p1[3] = pk2(a3[2], a3[3]);
    *(u32x4*)adst = p0;  *(u32x4*)(adst + 8) = p1;
    *(u32x4*)bdst = wv0; *(u32x4*)(bdst + 8) = wv1;
    __syncthreads();
    short8 af[4], bfr[4];
    #pragma unroll
    for (int mb = 0; mb < 4; ++mb)
      af[mb] = *(const short8*)(As + (wm * 64 + mb * 16 + l15) * GP + hi4 * 8);
    #pragma unroll
    for (int nb = 0; nb < 4; ++nb)
      bfr[nb] = *(const short8*)(Bs + (wn * 64 + nb * 16 + l15) * GP + hi4 * 8);
    #pragma unroll
    for (int mb = 0; mb < 4; ++mb)
      #pragma unroll
      for (int nb = 0; nb < 4; ++nb)
        acc[mb][nb] = mfma16(af[mb], bfr[nb], acc[mb][nb]);
    __syncthreads();
  }
  // epilogue: +bias, bf16, scatter into packed consumer layout
  #pragma unroll
  for (int nb = 0; nb < 4; ++nb) {
    int n = n0 + wn * 64 + nb * 16 + l15;
    int gate = n >> 9, hc = n & 511, wgc = hc >> 4, lcol = hc & 15;
    int gw2 = gate >> 1, gs2 = gate & 1;
    float bv = bias[n];
    #pragma unroll
    for (int mb = 0; mb < 4; ++mb) {
      int mbase = m0 + wm * 64 + mb * 16 + hi4 * 4;
      #pragma unroll
      for (int i = 0; i < 4; ++i) {
        int m = mbase + i;
        int tt = m & 1023, bb = m >> 10;
        int dd = bb >> 5, rloc = bb & 31;
        int mwc = rloc >> 4, chi = (rloc >> 2) & 3, cii = rloc & 3;
        size_t dst = ((((size_t)tt * 64 + dd * 32 + wgc) * 4 +
                       (mwc * 2 + gw2)) * 64 + (chi * 16 + lcol)) * 8 +
                     gs2 * 4 + cii;
        xp[dst] = f2bf(acc[mb][nb][i] + bv);
      }
    }
  }
}

// ---------------------------------------------------------------------------
// recurrence: 2 independent batch domains x 32 WGs. WG (d, wgl) owns domain
// d's 32 batch rows x h-cols [wgl*16, wgl*16+16). Wave w = (mw = w>>1 row
// half, gw = w&1 gate pair); Wh pair in 128 VGPRs. Per step:
//   dirty-mask sentinel poll (8 granules/thread, stage clean -> LDS swz,
//   re-issue only dirty) -> re-poison slot (t-2)%4 -> B1 -> 32 MFMA/wave ->
//   preact dump -> B2 -> combine (2 cols/thread) -> drain -> publish dword.
// One coherence hop per step; no flags, no fences, no full-tile re-polls.
// ---------------------------------------------------------------------------
#define AWAIT(N) do { \
  asm volatile("s_waitcnt vmcnt(" #N ")" ::: "memory"); \
  __builtin_amdgcn_sched_barrier(0); } while (0)

// single system-scope dwordx4 load, VGPR voffset + uniform SGPR base
#define PLD1(dst, vof, sb) \
  asm volatile("global_load_dwordx4 %0, %1, %2 sc0 sc1" \
               : "=v"(dst) : "v"(vof), "s"(sb))

// cached dwordx4 load via 64-bit VGPR address (divergence-safe)
#define XLD(dst, a64) \
  asm volatile("global_load_dwordx4 %0, %1, off" : "=v"(dst) : "v"(a64))

__global__ __launch_bounds__(256, 1) void lstm_rec(
    const unsigned short* __restrict__ xp, const unsigned short* __restrict__ WhT,
    unsigned short* __restrict__ hring, float* __restrict__ out)
{
  __shared__ unsigned short hA[16384];   // 32 KB staged h (XOR-swizzled)
  __shared__ float pre[4][32][17];       // 8.7 KB preact exchange

  int wgG = blockIdx.x;
  int d = wgG >> 5, wgl = wgG & 31;
  int tid = threadIdx.x, lane = tid & 63, w = tid >> 6;
  int mw = w >> 1, gw = w & 1;
  int l15 = lane & 15, hi4 = lane >> 4;

  // Wh fragments for this wave's 2 gates: 2 x 16 x short8 = 128 VGPR
  short8 bw[2][16];
  #pragma unroll
  for (int gs = 0; gs < 2; ++gs) {
    const unsigned short* wsrc =
        WhT + ((size_t)wgl * 64 + (gw * 2 + gs) * 16 + l15) * 512 + hi4 * 8;
    #pragma unroll
    for (int kk = 0; kk < 16; ++kk)
      bw[gs][kk] = *(const short8*)(wsrc + kk * 32);
  }

  // poll voffsets + swizzled LDS byte for this thread's 8 granules
  unsigned int voff[8], lbyt[8];
  #pragma unroll
  for (int k = 0; k < 8; ++k) {
    int gid = k * 256 + tid;
    int byt = gid * 16;
    int row = gid >> 6;
    voff[k] = (unsigned)byt;
    lbyt[k] = (unsigned)(byt ^ ((row & 7) << 4));
  }

  // gate-combine coordinates: 1 row x 2 consecutive local cols
  const int r = tid >> 3;
  const int cq = (tid & 7) * 2;
  float cst[2] = {0.f, 0.f};
  unsigned int vpub = (unsigned)(r * 1024 + wgl * 32 + cq * 2);

  // per-lane 64-bit xp address (this wave's 16B/lane packet for step t)
  unsigned long long xaddr = (unsigned long long)(uintptr_t)(
      xp + ((size_t)(wgG * 4 + w) * 64 + lane) * 8);

  u32x4 pc0, pn0;
  XLD(pc0, xaddr);

  const size_t dring = (size_t)d * 65536;    // domain base (elems)

  for (int t = 0; t < 1024; ++t) {
    const unsigned short* hb = hring + dring + ((size_t)(t & 3) << 14);
    // ---- dirty-mask sentinel poll + incremental staging ----
    u32x4 gb[8];
    {
      unsigned m = 0xFFu;
      int spins = 0;
      PLD1(gb[0], voff[0], hb); PLD1(gb[1], voff[1], hb);
      PLD1(gb[2], voff[2], hb); PLD1(gb[3], voff[3], hb);
      PLD1(gb[4], voff[4], hb); PLD1(gb[5], voff[5], hb);
      PLD1(gb[6], voff[6], hb); PLD1(gb[7], voff[7], hb);
      for (;;) {
        AWAIT(0);
        unsigned nm = 0;
        #pragma unroll
        for (int k = 0; k < 8; ++k) {
          if ((m >> k) & 1u) {
            u32x4 v = gb[k];
            bool clean = (v[0] != 0x80008000u) && (v[1] != 0x80008000u) &&
                         (v[2] != 0x80008000u) && (v[3] != 0x80008000u);
            if (clean)
              *(u32x4*)((char*)hA + lbyt[k]) = v;   // stage now
            else
              nm |= (1u << k);
          }
        }
        m = nm;
        if (m == 0u) break;
        if (++spins > (1 << 15)) break;   // bounded: fail visibly, never hang
        #pragma unroll
        for (int k = 0; k < 8; ++k)
          if ((m >> k) & 1u) PLD1(gb[k], voff[k], hb);
      }
    }
    // ---- re-poison slot (t-2)%4 (own slice; drained before publish) ----
    if (t >= 2) {
      const unsigned short* hp = hring + dring + ((size_t)((t - 2) & 3) << 14);
      unsigned int pv = 0x80008000u;
      asm volatile("global_store_dword %0, %1, %2 sc0 sc1"
                   :: "v"(vpub), "v"(pv), "s"(hp) : "memory");
    }
    __syncthreads();                // B1: staged h_t complete in LDS

    // ---- acc init from prefetched xp ----
    f32x4 acc[2];
    #pragma unroll
    for (int gs = 0; gs < 2; ++gs)
      #pragma unroll
      for (int i = 0; i < 4; ++i) {
        int j = gs * 4 + i;
        unsigned int dw = pc0[j >> 1];
        unsigned short us = (j & 1) ? (unsigned short)(dw >> 16)
                                    : (unsigned short)(dw & 0xFFFFu);
        acc[gs][i] = bf2f(us);
      }
    // prefetch next step's xp
    if (t < 1023) xaddr += 262144ULL;
    XLD(pn0, xaddr);

    // ---- MFMA: a-frags from swizzled LDS, b-frags from regs ----
    #pragma unroll
    for (int kk = 0; kk < 16; ++kk) {
      int r0 = mw * 16 + l15;
      int b0 = (r0 * 1024 + kk * 64 + hi4 * 16) ^ ((r0 & 7) << 4);
      short8 a0 = *(const short8*)((const char*)hA + b0);
      acc[0] = mfma16(a0, bw[0][kk], acc[0]);
      acc[1] = mfma16(a0, bw[1][kk], acc[1]);
    }

    // ---- preact dump ----
    #pragma unroll
    for (int gs = 0; gs < 2; ++gs)
      #pragma unroll
      for (int i = 0; i < 4; ++i)
        pre[gw * 2 + gs][mw * 16 + hi4 * 4 + i][l15] = acc[gs][i];
    __syncthreads();                // B2

    // ---- combine: row r, local cols cq..cq+1 ----
    float hv[2];
    #pragma unroll
    for (int i = 0; i < 2; ++i) {
      float fg = sigm(pre[0][r][cq + i]);
      float ig = sigm(pre[1][r][cq + i]);
      float gg = tanh_(pre[2][r][cq + i]);
      float og = sigm(pre[3][r][cq + i]);
      float c = fg * cst[i] + ig * gg;
      cst[i] = c;
      hv[i] = og * tanh_(c);
    }
    if (t < 1023) {
      AWAIT(0);                     // drain re-poison (+pn prefetch)
      const unsigned short* hbn =
          hring + dring + ((size_t)((t + 1) & 3) << 14);
      unsigned int u0 = f2bf(hv[0]), u1 = f2bf(hv[1]);
      if (u0 == 0x8000u) u0 = 0;    // cleanse -0.0 (poison)
      if (u1 == 0x8000u) u1 = 0;
      unsigned int pk = u0 | (u1 << 16);
      asm volatile("global_store_dword %0, %1, %2 sc0 sc1"
                   :: "v"(vpub), "v"(pk), "s"(hbn) : "memory");
    } else {
      int b = d * 32 + r, col = wgl * 16 + cq;
      out[(size_t)b * 512 + col] = hv[0];
      out[(size_t)b * 512 + col + 1] = hv[1];
      out[32768 + (size_t)b * 512 + col] = cst[0];
      out[32768 + (size_t)b * 512 + col + 1] = cst[1];
    }
    pc0 = pn0;
  }
}

// ---------------------------------------------------------------------------
extern "C" void kernel_launch(void* const* d_in, const int* in_sizes, int n_in,
                              void* d_out, int out_size, void* d_ws, size_t ws_size,
                              hipStream_t stream) {
  const float* x   = (const float*)d_in[0];
  const float* Wii = (const float*)d_in[1];
  const float* Whi = (const float*)d_in[2];
  const float* Wif = (const float*)d_in[3];
  const float* Whf = (const float*)d_in[4];
  const float* Wig = (const float*)d_in[5];
  const float* Whg = (const float*)d_in[6];
  const float* Wio = (const float*)d_in[7];
  const float* Who = (const float*)d_in[8];
  const float* bii = (const float*)d_in[9];
  const float* bhi = (const float*)d_in[10];
  const float* bif = (const float*)d_in[11];
  const float* bhf = (const float*)d_in[12];
  const float* big = (const float*)d_in[13];
  const float* bhg = (const float*)d_in[14];
  const float* bio = (const float*)d_in[15];
  const float* bho = (const float*)d_in[16];

  char* ws = (char*)d_ws;
  size_t off = 0;
  auto alloc = [&](size_t bytes) {
    size_t p = off; off = (off + bytes + 255) & ~(size_t)255; return p;
  };
  unsigned short* WxT  = (unsigned short*)(ws + alloc(2048UL * 512 * 2));
  unsigned short* WhT  = (unsigned short*)(ws + alloc(32UL * 64 * 512 * 2));
  float*          bias = (float*)        (ws + alloc(2048UL * 4));
  unsigned short* hring= (unsigned short*)(ws + alloc(2UL * 4 * 32 * 512 * 2));
  unsigned short* xpb  = (unsigned short*)(ws + alloc(1024UL * 64 * 2048 * 2));
  if (off > ws_size) return;  // insufficient workspace -> fail visibly

  lstm_prep<<<2048, 256, 0, stream>>>(Wif, Wii, Wig, Wio, Whf, Whi, Whg, Who,
                                      bif, bhf, bii, bhi, big, bhg, bio, bho,
                                      WxT, WhT, bias, hring);
  lstm_xproj<<<8192, 256, 0, stream>>>(x, WxT, bias, xpb);
  lstm_rec<<<64, 256, 0, stream>>>(xpb, WhT, hring, (float*)d_out);
}